// Round 10
// baseline (313.015 us; speedup 1.0000x reference)
//
#include <hip/hip_runtime.h>

#define NN 50000
#define EE 800000
#define ETOT (EE + NN)
#define GEMM_GRID 391      // x2 M-tiles each = 782
#define MTILES 782         // ceil(NN/64)
#define COUNT_BLOCKS 3125  // EE/256 exactly
#define AGG_BLOCKS 1280    // 5 blocks/CU (32KB LDS each)
#define SCAN_BLOCKS 196    // ceil(NN/256)

typedef __attribute__((ext_vector_type(8))) short bhalf8;  // 8 bf16 (4 VGPR)
typedef __attribute__((ext_vector_type(4))) float fx4;     // mfma acc

__device__ __forceinline__ unsigned bf16r(float f) {  // RNE float->bf16 bits
  unsigned u = __float_as_uint(f);
  return (u + 0x7FFFu + ((u >> 16) & 1u)) >> 16;
}

__device__ __forceinline__ float4 unpack_bf16x4(unsigned a, unsigned b) {
  float4 f;
  f.x = __uint_as_float(a << 16);
  f.y = __uint_as_float(a & 0xFFFF0000u);
  f.z = __uint_as_float(b << 16);
  f.w = __uint_as_float(b & 0xFFFF0000u);
  return f;
}

#define GLOAD_LDS16(gp, lp)                                          \
  __builtin_amdgcn_global_load_lds(                                  \
      (const __attribute__((address_space(1))) void*)(gp),           \
      (__attribute__((address_space(3))) void*)(lp), 16, 0, 0)

// ---- fused: MFMA GEMM (blocks 0..390) | degree count (blocks 391..3515) ----
__global__ __launch_bounds__(256) void gemm_count(
    const float* __restrict__ x,
    const float* __restrict__ Wl, const float* __restrict__ bl,
    const float* __restrict__ Wr, const float* __restrict__ br,
    unsigned short* __restrict__ xlh, float* __restrict__ xr,
    const int* __restrict__ ei, int* __restrict__ deg) {
  if (blockIdx.x >= GEMM_GRID) {
    int e = (blockIdx.x - GEMM_GRID) * 256 + threadIdx.x;
    if (e < EE) atomicAdd(&deg[ei[EE + e]], 1);
    return;
  }
  __shared__ unsigned short sW[256 * 136];
  const int t = threadIdx.x;
  const int w = t >> 6;
  const int l = t & 63;
  const int cl = l & 15;
  const int kb = (l >> 4) * 8;
  const int rsub = (l >> 4) * 4;

#pragma unroll
  for (int it = 0; it < 16; ++it) {
    int f4 = t + it * 256;
    int k = f4 >> 5;
    int c4 = (f4 & 31) * 4;
    float4 v = *(const float4*)&Wl[(size_t)k * 128 + c4];
    sW[(c4 + 0) * 136 + k] = (unsigned short)bf16r(v.x);
    sW[(c4 + 1) * 136 + k] = (unsigned short)bf16r(v.y);
    sW[(c4 + 2) * 136 + k] = (unsigned short)bf16r(v.z);
    sW[(c4 + 3) * 136 + k] = (unsigned short)bf16r(v.w);
    float4 u = *(const float4*)&Wr[(size_t)k * 128 + c4];
    sW[(128 + c4 + 0) * 136 + k] = (unsigned short)bf16r(u.x);
    sW[(128 + c4 + 1) * 136 + k] = (unsigned short)bf16r(u.y);
    sW[(128 + c4 + 2) * 136 + k] = (unsigned short)bf16r(u.z);
    sW[(128 + c4 + 3) * 136 + k] = (unsigned short)bf16r(u.w);
  }
  __syncthreads();

  bhalf8 bfr[4][4];
  float biasv[4];
#pragma unroll
  for (int nt = 0; nt < 4; ++nt) {
    int col = w * 64 + nt * 16 + cl;
    biasv[nt] = (col < 128) ? bl[col] : br[col - 128];
#pragma unroll
    for (int ch = 0; ch < 4; ++ch)
      bfr[nt][ch] = *(const bhalf8*)&sW[col * 136 + ch * 32 + kb];
  }

  for (int mt = blockIdx.x; mt < MTILES; mt += GEMM_GRID) {
    const int m0 = mt * 64;
#pragma unroll
    for (int rt = 0; rt < 4; ++rt) {
      int row = m0 + rt * 16 + cl;
      int rowc = row < NN ? row : NN - 1;
      const float* xp = x + (size_t)rowc * 128 + kb;
      bhalf8 afr[4];
#pragma unroll
      for (int ch = 0; ch < 4; ++ch) {
        float4 q0 = *(const float4*)(xp + ch * 32);
        float4 q1 = *(const float4*)(xp + ch * 32 + 4);
        bhalf8 f;
        f[0] = (short)bf16r(q0.x); f[1] = (short)bf16r(q0.y);
        f[2] = (short)bf16r(q0.z); f[3] = (short)bf16r(q0.w);
        f[4] = (short)bf16r(q1.x); f[5] = (short)bf16r(q1.y);
        f[6] = (short)bf16r(q1.z); f[7] = (short)bf16r(q1.w);
        afr[ch] = f;
      }
#pragma unroll
      for (int nt = 0; nt < 4; ++nt) {
        fx4 acc = {biasv[nt], biasv[nt], biasv[nt], biasv[nt]};
#pragma unroll
        for (int ch = 0; ch < 4; ++ch)
          acc = __builtin_amdgcn_mfma_f32_16x16x32_bf16(afr[ch], bfr[nt][ch],
                                                        acc, 0, 0, 0);
        int col = w * 64 + nt * 16 + cl;
        int rbase = m0 + rt * 16 + rsub;
        if (col < 128) {
#pragma unroll
          for (int r = 0; r < 4; ++r) {
            int rr = rbase + r;
            if (rr < NN) xlh[(size_t)rr * 128 + col] = (unsigned short)bf16r(acc[r]);
          }
        } else {
          int c2 = col - 128;
#pragma unroll
          for (int r = 0; r < 4; ++r) {
            int rr = rbase + r;
            if (rr < NN) xr[(size_t)rr * 128 + c2] = acc[r];
          }
        }
      }
    }
  }
}

// ---------------- scanA: per-block reduce of deg; zero bn ----------------
__global__ __launch_bounds__(256) void scanA(const int* __restrict__ deg,
                                             int* __restrict__ bsum,
                                             float* __restrict__ bn) {
  __shared__ int s[256];
  int t = threadIdx.x;
  if (blockIdx.x == 0) bn[t] = 0.f;
  int i = blockIdx.x * 256 + t;
  s[t] = (i < NN) ? deg[i] : 0;
  __syncthreads();
#pragma unroll
  for (int off = 128; off > 0; off >>= 1) {
    if (t < off) s[t] += s[t + off];
    __syncthreads();
  }
  if (t == 0) bsum[blockIdx.x] = s[0];
}

// -------- scanB: redundant block-prefix + local scan -> offs / cursor -------
__global__ __launch_bounds__(256) void scanB(const int* __restrict__ deg,
                                             const int* __restrict__ bsum,
                                             int* __restrict__ offs,
                                             int* __restrict__ cursor) {
  __shared__ int s[256];
  __shared__ int bpref;
  int t = threadIdx.x;
  int bid = blockIdx.x;
  int i = bid * 256 + t;
  int v = (i < NN) ? deg[i] : 0;
  s[t] = v;
  if (t == 0) {
    int r = 0;
    for (int k = 0; k < bid; ++k) r += bsum[k];
    bpref = r;
  }
  __syncthreads();
  for (int off = 1; off < 256; off <<= 1) {
    int u = (t >= off) ? s[t - off] : 0;
    __syncthreads();
    s[t] += u;
    __syncthreads();
  }
  int excl = s[t] - v + bpref;
  if (i <= NN) {
    offs[i] = excl;
    if (i < NN) cursor[i] = excl;
  }
}

__global__ void fill_csr(const int* __restrict__ ei, int* __restrict__ cursor,
                         int* __restrict__ csr) {
  int e = blockIdx.x * 256 + threadIdx.x;
  if (e >= ETOT) return;
  int s, d;
  if (e < EE) { s = ei[e]; d = ei[EE + e]; }
  else { s = e - EE; d = s; }
  int pos = atomicAdd(&cursor[d], 1);
  csr[pos] = s;
}

// ---------------- fused score + segment-softmax (max-free) + aggregation ----
// One node per 16-lane group, 4 nodes per wave. Row gathers staged via
// global_load_lds into an 8-slot circular LDS buffer. PIPELINE DEPTH = 7:
// with 8 slots, depth 8 made STAGE(i+8) write slot i&7 while CONSUME(i) read
// it (OOO DMA landed early) -> R8's absmax 8.2. Depth 7 keeps the staged slot
// disjoint from all 7 unconsumed slots. Counted s_waitcnt vmcnt(7), never 0
// in steady state.
__global__ __launch_bounds__(256, 8) void aggregate(
    const unsigned short* __restrict__ xlh, const float* __restrict__ xr,
    const int* __restrict__ offs, const int* __restrict__ csr,
    const float* __restrict__ att, float* __restrict__ out) {
  __shared__ __align__(16) unsigned char stg[4][8][1024];  // 32 KB
  const int t = threadIdx.x;
  const int w = t >> 6;
  const int l = t & 63;
  const int g = l >> 4;
  const int gl = l & 15;
  const int gb = l & 48;
  const int c8 = gl * 8;
  unsigned char* wbase = &stg[w][0][0];
  const float4 at0 = *(const float4*)&att[c8];
  const float4 at1 = *(const float4*)&att[c8 + 4];
  const int wgid = blockIdx.x * 4 + w;
  const int nstride = gridDim.x * 16;  // nodes per sweep

  for (int nb = wgid * 4; nb < NN; nb += nstride) {
    const int node = nb + g;
    const int nodec = node < NN ? node : NN - 1;
    const float4 xr0 = *(const float4*)&xr[(size_t)nodec * 128 + c8];
    const float4 xr1 = *(const float4*)&xr[(size_t)nodec * 128 + c8 + 4];
    const int beg = offs[nodec];
    int deg = offs[nodec + 1] - beg;
    if (node >= NN) deg = 0;
    int maxd = deg;
    maxd = max(maxd, __shfl_xor(maxd, 16));
    maxd = max(maxd, __shfl_xor(maxd, 32));

    // upfront csr chunks (rows 0..63); clamped reads, garbage rows masked later
    int m0, m1, m2, m3;
    { int a = beg + gl;      a = a < ETOT ? a : ETOT - 1; m0 = csr[a]; }
    m1 = m0; m2 = m0; m3 = m0;
    if (maxd > 16) { int a = beg + 16 + gl; a = a < ETOT ? a : ETOT - 1; m1 = csr[a]; }
    if (maxd > 32) { int a = beg + 32 + gl; a = a < ETOT ? a : ETOT - 1; m2 = csr[a]; }
    if (maxd > 48) { int a = beg + 48 + gl; a = a < ETOT ? a : ETOT - 1; m3 = csr[a]; }

    // force xr (and m*) waits to land HERE, before the pipeline starts
    float xtouch = xr0.x + xr1.x;
    asm volatile("" :: "v"(xtouch));

    float den = 0.f;
    float4 a0 = make_float4(0, 0, 0, 0), a1 = make_float4(0, 0, 0, 0);

#define STAGE(i) do {                                                      \
      int ii = (i);                                                        \
      int cr = ii < 16 ? m0 : ii < 32 ? m1 : ii < 48 ? m2 : m3;            \
      int s = __shfl(cr, gb + (ii & 15), 64);                              \
      if (ii >= deg) s = 0;                                                \
      GLOAD_LDS16(xlh + (size_t)s * 128 + c8,                              \
                  wbase + (((unsigned)(ii)&7u) << 10));                    \
    } while (0)

#define CONSUME(i) do {                                                    \
      uint4 u = *(const uint4*)(wbase + (((unsigned)(i)&7u) << 10) + l * 16); \
      float4 v0 = unpack_bf16x4(u.x, u.y);                                 \
      float4 v1 = unpack_bf16x4(u.z, u.w);                                 \
      float e, p;                                                          \
      e = v0.x + xr0.x; e = e > 0.f ? e : 0.2f * e; p = e * at0.x;         \
      e = v0.y + xr0.y; e = e > 0.f ? e : 0.2f * e; p = fmaf(e, at0.y, p); \
      e = v0.z + xr0.z; e = e > 0.f ? e : 0.2f * e; p = fmaf(e, at0.z, p); \
      e = v0.w + xr0.w; e = e > 0.f ? e : 0.2f * e; p = fmaf(e, at0.w, p); \
      e = v1.x + xr1.x; e = e > 0.f ? e : 0.2f * e; p = fmaf(e, at1.x, p); \
      e = v1.y + xr1.y; e = e > 0.f ? e : 0.2f * e; p = fmaf(e, at1.y, p); \
      e = v1.z + xr1.z; e = e > 0.f ? e : 0.2f * e; p = fmaf(e, at1.z, p); \
      e = v1.w + xr1.w; e = e > 0.f ? e : 0.2f * e; p = fmaf(e, at1.w, p); \
      p += __shfl_xor(p, 1);                                               \
      p += __shfl_xor(p, 2);                                               \
      float pe = ((i) < deg) ? __expf(p) : 0.f;                            \
      den += pe;                                                           \
      a0.x = fmaf(pe, v0.x, a0.x); a0.y = fmaf(pe, v0.y, a0.y);            \
      a0.z = fmaf(pe, v0.z, a0.z); a0.w = fmaf(pe, v0.w, a0.w);            \
      a1.x = fmaf(pe, v1.x, a1.x); a1.y = fmaf(pe, v1.y, a1.y);            \
      a1.z = fmaf(pe, v1.z, a1.z); a1.w = fmaf(pe, v1.w, a1.w);            \
    } while (0)

    const int mp = maxd < 64 ? maxd : 64;  // pipelined region
    const int pro = mp < 7 ? mp : 7;       // depth 7 < 8 slots (no collision)
    for (int i = 0; i < pro; ++i) STAGE(i);
    const int me = mp - 7;  // may be <= 0
    for (int i = 0; i < me; ++i) {
      STAGE(i + 7);
      asm volatile("s_waitcnt vmcnt(7)" ::: "memory");
      CONSUME(i);
    }
    asm volatile("s_waitcnt vmcnt(0)" ::: "memory");
    for (int i = me > 0 ? me : 0; i < mp; ++i) CONSUME(i);

    // rare deg>64 tail: direct register gathers, unpipelined
    for (int i = 64; i < maxd; ++i) {
      int a = beg + i; a = a < ETOT ? a : ETOT - 1;
      int s = csr[a];
      if (i >= deg) s = 0;
      uint4 u = *(const uint4*)(xlh + (size_t)s * 128 + c8);
      float4 v0 = unpack_bf16x4(u.x, u.y);
      float4 v1 = unpack_bf16x4(u.z, u.w);
      float e, p;
      e = v0.x + xr0.x; e = e > 0.f ? e : 0.2f * e; p = e * at0.x;
      e = v0.y + xr0.y; e = e > 0.f ? e : 0.2f * e; p = fmaf(e, at0.y, p);
      e = v0.z + xr0.z; e = e > 0.f ? e : 0.2f * e; p = fmaf(e, at0.z, p);
      e = v0.w + xr0.w; e = e > 0.f ? e : 0.2f * e; p = fmaf(e, at0.w, p);
      e = v1.x + xr1.x; e = e > 0.f ? e : 0.2f * e; p = fmaf(e, at1.x, p);
      e = v1.y + xr1.y; e = e > 0.f ? e : 0.2f * e; p = fmaf(e, at1.y, p);
      e = v1.z + xr1.z; e = e > 0.f ? e : 0.2f * e; p = fmaf(e, at1.z, p);
      e = v1.w + xr1.w; e = e > 0.f ? e : 0.2f * e; p = fmaf(e, at1.w, p);
      p += __shfl_xor(p, 1);
      p += __shfl_xor(p, 2);
      float pe = (i < deg) ? __expf(p) : 0.f;
      den += pe;
      a0.x = fmaf(pe, v0.x, a0.x); a0.y = fmaf(pe, v0.y, a0.y);
      a0.z = fmaf(pe, v0.z, a0.z); a0.w = fmaf(pe, v0.w, a0.w);
      a1.x = fmaf(pe, v1.x, a1.x); a1.y = fmaf(pe, v1.y, a1.y);
      a1.z = fmaf(pe, v1.z, a1.z); a1.w = fmaf(pe, v1.w, a1.w);
    }
#undef STAGE
#undef CONSUME

    if (node < NN) {
      float inv = 1.0f / den;
      float4 r0, r1;
      r0.x = a0.x * inv; r0.y = a0.y * inv; r0.z = a0.z * inv; r0.w = a0.w * inv;
      r1.x = a1.x * inv; r1.y = a1.y * inv; r1.z = a1.z * inv; r1.w = a1.w * inv;
      *(float4*)&out[(size_t)node * 128 + c8] = r0;
      *(float4*)&out[(size_t)node * 128 + c8 + 4] = r1;
    }
  }
}

// ---------------- BN stats over out (sum, sumsq per channel) ----------------
__global__ __launch_bounds__(256) void bn_stats(const float* __restrict__ out,
                                                float* __restrict__ bn) {
  __shared__ float sb[256];
  int t = threadIdx.x;
  sb[t] = 0.f;
  __syncthreads();
  const int c4 = (t & 31) * 4;
  float4 s = make_float4(0, 0, 0, 0), q = make_float4(0, 0, 0, 0);
  const int total4 = NN * 32;
  for (int i = blockIdx.x * 256 + t; i < total4; i += gridDim.x * 256) {
    float4 o = ((const float4*)out)[i];
    s.x += o.x; s.y += o.y; s.z += o.z; s.w += o.w;
    q.x += o.x * o.x; q.y += o.y * o.y; q.z += o.z * o.z; q.w += o.w * o.w;
  }
  atomicAdd(&sb[c4 + 0], s.x);
  atomicAdd(&sb[c4 + 1], s.y);
  atomicAdd(&sb[c4 + 2], s.z);
  atomicAdd(&sb[c4 + 3], s.w);
  atomicAdd(&sb[128 + c4 + 0], q.x);
  atomicAdd(&sb[128 + c4 + 1], q.y);
  atomicAdd(&sb[128 + c4 + 2], q.z);
  atomicAdd(&sb[128 + c4 + 3], q.w);
  __syncthreads();
  atomicAdd(&bn[t], sb[t]);
}

// ---------------- BN-normalize + residual + ELU (in place on d_out) ----------
__global__ __launch_bounds__(256) void finalize(
    float* __restrict__ out, const float* __restrict__ x,
    const float* __restrict__ bn, const float* __restrict__ gamma,
    const float* __restrict__ beta) {
  __shared__ float smu[128], sgi[128];
  int t = threadIdx.x;
  if (t < 128) {
    float mu = bn[t] * (1.0f / NN);
    float var = bn[128 + t] * (1.0f / NN) - mu * mu;
    smu[t] = mu;
    sgi[t] = rsqrtf(var + 1e-5f) * gamma[t];
  }
  __syncthreads();
  const int total4 = NN * 32;
  for (int i = blockIdx.x * blockDim.x + threadIdx.x; i < total4;
       i += gridDim.x * blockDim.x) {
    int c4 = (i & 31) * 4;
    float4 o = ((const float4*)out)[i];
    float4 xv = ((const float4*)x)[i];
    float4 mu = *(const float4*)&smu[c4];
    float4 gi = *(const float4*)&sgi[c4];
    float4 b4 = *(const float4*)&beta[c4];
    float v;
    v = (o.x - mu.x) * gi.x + b4.x + xv.x; o.x = v > 0.f ? v : expm1f(v);
    v = (o.y - mu.y) * gi.y + b4.y + xv.y; o.y = v > 0.f ? v : expm1f(v);
    v = (o.z - mu.z) * gi.z + b4.z + xv.z; o.z = v > 0.f ? v : expm1f(v);
    v = (o.w - mu.w) * gi.w + b4.w + xv.w; o.w = v > 0.f ? v : expm1f(v);
    ((float4*)out)[i] = o;
  }
}

extern "C" void kernel_launch(void* const* d_in, const int* in_sizes, int n_in,
                              void* d_out, int out_size, void* d_ws, size_t ws_size,
                              hipStream_t stream) {
  const float* x    = (const float*)d_in[0];
  const int*   ei   = (const int*)d_in[1];
  const float* Wl   = (const float*)d_in[2];
  const float* bl   = (const float*)d_in[3];
  const float* Wr   = (const float*)d_in[4];
  const float* br   = (const float*)d_in[5];
  const float* att  = (const float*)d_in[6];
  const float* gam  = (const float*)d_in[8];
  const float* bet  = (const float*)d_in[9];
  float* out = (float*)d_out;

  unsigned short* xlh = (unsigned short*)d_ws;        // NN*128 bf16
  float* xr   = (float*)(xlh + (size_t)NN * 128);     // NN*128 f32
  int* offs   = (int*)(xr + (size_t)NN * 128);        // NN+4 ints
  int* cursor = offs + (NN + 4);                      // NN ints
  int* deg    = cursor + NN;                          // NN ints
  int* csr    = deg + NN;                             // ETOT ints
  float* bn   = (float*)(csr + ETOT);                 // 256 f32: sum | sumsq
  int* bsum   = (int*)(bn + 256);                     // 256 ints

  hipMemsetD32Async((hipDeviceptr_t)deg, 1, NN, stream);  // self-loop

  hipLaunchKernelGGL(gemm_count, dim3(GEMM_GRID + COUNT_BLOCKS), dim3(256), 0,
                     stream, x, Wl, bl, Wr, br, xlh, xr, ei, deg);
  hipLaunchKernelGGL(scanA, dim3(SCAN_BLOCKS), dim3(256), 0, stream, deg, bsum, bn);
  hipLaunchKernelGGL(scanB, dim3(SCAN_BLOCKS), dim3(256), 0, stream,
                     deg, bsum, offs, cursor);
  hipLaunchKernelGGL(fill_csr, dim3((ETOT + 255) / 256), dim3(256), 0, stream,
                     ei, cursor, csr);
  hipLaunchKernelGGL(aggregate, dim3(AGG_BLOCKS), dim3(256), 0, stream,
                     xlh, xr, offs, csr, att, out);
  hipLaunchKernelGGL(bn_stats, dim3(1024), dim3(256), 0, stream, out, bn);
  hipLaunchKernelGGL(finalize, dim3(2048), dim3(256), 0, stream, out, x, bn, gam, bet);
}

// Round 11
// 306.340 us; speedup vs baseline: 1.0218x; 1.0218x over previous
//
#include <hip/hip_runtime.h>

#define NN 50000
#define EE 800000
#define ETOT (EE + NN)
#define GEMM_GRID 391      // x2 M-tiles each = 782
#define MTILES 782         // ceil(NN/64)
#define COUNT_BLOCKS 3125  // EE/256 exactly
#define AGG_BLOCKS 1280    // 5 blocks/CU (32KB LDS each)
#define SCAN_BLOCKS 196    // ceil(NN/256)

typedef __attribute__((ext_vector_type(8))) short bhalf8;  // 8 bf16 (4 VGPR)
typedef __attribute__((ext_vector_type(4))) float fx4;     // mfma acc

__device__ __forceinline__ unsigned bf16r(float f) {  // RNE float->bf16 bits
  unsigned u = __float_as_uint(f);
  return (u + 0x7FFFu + ((u >> 16) & 1u)) >> 16;
}

__device__ __forceinline__ float4 unpack_bf16x4(unsigned a, unsigned b) {
  float4 f;
  f.x = __uint_as_float(a << 16);
  f.y = __uint_as_float(a & 0xFFFF0000u);
  f.z = __uint_as_float(b << 16);
  f.w = __uint_as_float(b & 0xFFFF0000u);
  return f;
}

// sum within 4-lane quads via DPP quad_perm (VALU, no LDS pipe):
// xor1 = [1,0,3,2] = 0xB1 ; xor2 = [2,3,0,1] = 0x4E
__device__ __forceinline__ float quad_red(float p) {
  p += __int_as_float(__builtin_amdgcn_mov_dpp(__float_as_int(p), 0xB1, 0xF, 0xF, true));
  p += __int_as_float(__builtin_amdgcn_mov_dpp(__float_as_int(p), 0x4E, 0xF, 0xF, true));
  return p;
}

#define GLOAD_LDS16(gp, lp)                                          \
  __builtin_amdgcn_global_load_lds(                                  \
      (const __attribute__((address_space(1))) void*)(gp),           \
      (__attribute__((address_space(3))) void*)(lp), 16, 0, 0)

// ---- fused: MFMA GEMM (blocks 0..390) | degree count (blocks 391..3515) ----
__global__ __launch_bounds__(256) void gemm_count(
    const float* __restrict__ x,
    const float* __restrict__ Wl, const float* __restrict__ bl,
    const float* __restrict__ Wr, const float* __restrict__ br,
    unsigned short* __restrict__ xlh, float* __restrict__ xr,
    const int* __restrict__ ei, int* __restrict__ deg) {
  if (blockIdx.x >= GEMM_GRID) {
    int e = (blockIdx.x - GEMM_GRID) * 256 + threadIdx.x;
    if (e < EE) atomicAdd(&deg[ei[EE + e]], 1);
    return;
  }
  __shared__ unsigned short sW[256 * 136];
  const int t = threadIdx.x;
  const int w = t >> 6;
  const int l = t & 63;
  const int cl = l & 15;
  const int kb = (l >> 4) * 8;
  const int rsub = (l >> 4) * 4;

#pragma unroll
  for (int it = 0; it < 16; ++it) {
    int f4 = t + it * 256;
    int k = f4 >> 5;
    int c4 = (f4 & 31) * 4;
    float4 v = *(const float4*)&Wl[(size_t)k * 128 + c4];
    sW[(c4 + 0) * 136 + k] = (unsigned short)bf16r(v.x);
    sW[(c4 + 1) * 136 + k] = (unsigned short)bf16r(v.y);
    sW[(c4 + 2) * 136 + k] = (unsigned short)bf16r(v.z);
    sW[(c4 + 3) * 136 + k] = (unsigned short)bf16r(v.w);
    float4 u = *(const float4*)&Wr[(size_t)k * 128 + c4];
    sW[(128 + c4 + 0) * 136 + k] = (unsigned short)bf16r(u.x);
    sW[(128 + c4 + 1) * 136 + k] = (unsigned short)bf16r(u.y);
    sW[(128 + c4 + 2) * 136 + k] = (unsigned short)bf16r(u.z);
    sW[(128 + c4 + 3) * 136 + k] = (unsigned short)bf16r(u.w);
  }
  __syncthreads();

  bhalf8 bfr[4][4];
  float biasv[4];
#pragma unroll
  for (int nt = 0; nt < 4; ++nt) {
    int col = w * 64 + nt * 16 + cl;
    biasv[nt] = (col < 128) ? bl[col] : br[col - 128];
#pragma unroll
    for (int ch = 0; ch < 4; ++ch)
      bfr[nt][ch] = *(const bhalf8*)&sW[col * 136 + ch * 32 + kb];
  }

  for (int mt = blockIdx.x; mt < MTILES; mt += GEMM_GRID) {
    const int m0 = mt * 64;
#pragma unroll
    for (int rt = 0; rt < 4; ++rt) {
      int row = m0 + rt * 16 + cl;
      int rowc = row < NN ? row : NN - 1;
      const float* xp = x + (size_t)rowc * 128 + kb;
      bhalf8 afr[4];
#pragma unroll
      for (int ch = 0; ch < 4; ++ch) {
        float4 q0 = *(const float4*)(xp + ch * 32);
        float4 q1 = *(const float4*)(xp + ch * 32 + 4);
        bhalf8 f;
        f[0] = (short)bf16r(q0.x); f[1] = (short)bf16r(q0.y);
        f[2] = (short)bf16r(q0.z); f[3] = (short)bf16r(q0.w);
        f[4] = (short)bf16r(q1.x); f[5] = (short)bf16r(q1.y);
        f[6] = (short)bf16r(q1.z); f[7] = (short)bf16r(q1.w);
        afr[ch] = f;
      }
#pragma unroll
      for (int nt = 0; nt < 4; ++nt) {
        fx4 acc = {biasv[nt], biasv[nt], biasv[nt], biasv[nt]};
#pragma unroll
        for (int ch = 0; ch < 4; ++ch)
          acc = __builtin_amdgcn_mfma_f32_16x16x32_bf16(afr[ch], bfr[nt][ch],
                                                        acc, 0, 0, 0);
        int col = w * 64 + nt * 16 + cl;
        int rbase = m0 + rt * 16 + rsub;
        if (col < 128) {
#pragma unroll
          for (int r = 0; r < 4; ++r) {
            int rr = rbase + r;
            if (rr < NN) xlh[(size_t)rr * 128 + col] = (unsigned short)bf16r(acc[r]);
          }
        } else {
          int c2 = col - 128;
#pragma unroll
          for (int r = 0; r < 4; ++r) {
            int rr = rbase + r;
            if (rr < NN) xr[(size_t)rr * 128 + c2] = acc[r];
          }
        }
      }
    }
  }
}

// ---------------- scanA: per-block reduce of deg; zero bn ----------------
__global__ __launch_bounds__(256) void scanA(const int* __restrict__ deg,
                                             int* __restrict__ bsum,
                                             float* __restrict__ bn) {
  __shared__ int s[256];
  int t = threadIdx.x;
  if (blockIdx.x == 0) bn[t] = 0.f;
  int i = blockIdx.x * 256 + t;
  s[t] = (i < NN) ? deg[i] : 0;
  __syncthreads();
#pragma unroll
  for (int off = 128; off > 0; off >>= 1) {
    if (t < off) s[t] += s[t + off];
    __syncthreads();
  }
  if (t == 0) bsum[blockIdx.x] = s[0];
}

// -------- scanB: redundant block-prefix + local scan -> offs / cursor -------
__global__ __launch_bounds__(256) void scanB(const int* __restrict__ deg,
                                             const int* __restrict__ bsum,
                                             int* __restrict__ offs,
                                             int* __restrict__ cursor) {
  __shared__ int s[256];
  __shared__ int bpref;
  int t = threadIdx.x;
  int bid = blockIdx.x;
  int i = bid * 256 + t;
  int v = (i < NN) ? deg[i] : 0;
  s[t] = v;
  if (t == 0) {
    int r = 0;
    for (int k = 0; k < bid; ++k) r += bsum[k];
    bpref = r;
  }
  __syncthreads();
  for (int off = 1; off < 256; off <<= 1) {
    int u = (t >= off) ? s[t - off] : 0;
    __syncthreads();
    s[t] += u;
    __syncthreads();
  }
  int excl = s[t] - v + bpref;
  if (i <= NN) {
    offs[i] = excl;
    if (i < NN) cursor[i] = excl;
  }
}

__global__ void fill_csr(const int* __restrict__ ei, int* __restrict__ cursor,
                         int* __restrict__ csr) {
  int e = blockIdx.x * 256 + threadIdx.x;
  if (e >= ETOT) return;
  int s, d;
  if (e < EE) { s = ei[e]; d = ei[EE + e]; }
  else { s = e - EE; d = s; }
  int pos = atomicAdd(&cursor[d], 1);
  csr[pos] = s;
}

// ---------------- fused score + segment-softmax (max-free) + aggregation ----
// One node per 16-lane group, 4 nodes per wave. global_load_lds staging into
// 8 LDS slots, pipeline depth 7, counted vmcnt(7). R10 changes:
//  - head-quad score reduce via DPP quad_perm (no LDS pipe, no lgkm wait)
//  - leaky = fmaxf(e, 0.2e)
//  - next-node meta (offs/xr/csr) prefetched BEFORE the drain; its latency
//    hides under vmcnt(0)+tail consumes+prologue. maxd2's shfl deferred to
//    after the tail so its lgkm wait is free.
__global__ __launch_bounds__(256, 8) void aggregate(
    const unsigned short* __restrict__ xlh, const float* __restrict__ xr,
    const int* __restrict__ offs, const int* __restrict__ csr,
    const float* __restrict__ att, float* __restrict__ out) {
  __shared__ __align__(16) unsigned char stg[4][8][1024];  // 32 KB
  const int t = threadIdx.x;
  const int w = t >> 6;
  const int l = t & 63;
  const int g = l >> 4;
  const int gl = l & 15;
  const int gb = l & 48;
  const int c8 = gl * 8;
  unsigned char* wbase = &stg[w][0][0];
  const float4 at0 = *(const float4*)&att[c8];
  const float4 at1 = *(const float4*)&att[c8 + 4];
  const int wgid = blockIdx.x * 4 + w;
  const int nstride = gridDim.x * 16;  // nodes per sweep

  // ---- meta for first node ----
  int nb = wgid * 4;
  int node = nb + g;
  int nodec = node < NN ? node : NN - 1;
  float4 xr0 = *(const float4*)&xr[(size_t)nodec * 128 + c8];
  float4 xr1 = *(const float4*)&xr[(size_t)nodec * 128 + c8 + 4];
  int beg = offs[nodec];
  int deg = offs[nodec + 1] - beg;
  if (node >= NN) deg = 0;
  int maxd = deg;
  maxd = max(maxd, __shfl_xor(maxd, 16));
  maxd = max(maxd, __shfl_xor(maxd, 32));
  int m0, m1, m2, m3;
  { int a = beg + gl;      a = a < ETOT ? a : ETOT - 1; m0 = csr[a]; }
  { int a = beg + 16 + gl; a = a < ETOT ? a : ETOT - 1; m1 = csr[a]; }
  { int a = beg + 32 + gl; a = a < ETOT ? a : ETOT - 1; m2 = csr[a]; }
  { int a = beg + 48 + gl; a = a < ETOT ? a : ETOT - 1; m3 = csr[a]; }

  for (; nb < NN; nb += nstride) {
    // force current meta waits to land here, before the pipeline starts
    float xtouch = xr0.x + xr1.x;
    asm volatile("" :: "v"(xtouch));

    float den = 0.f;
    float4 a0 = make_float4(0, 0, 0, 0), a1 = make_float4(0, 0, 0, 0);

#define STAGE(i) do {                                                      \
      int ii = (i);                                                        \
      int cr = ii < 16 ? m0 : ii < 32 ? m1 : ii < 48 ? m2 : m3;            \
      int s = __shfl(cr, gb + (ii & 15), 64);                              \
      if (ii >= deg) s = 0;                                                \
      GLOAD_LDS16(xlh + (size_t)s * 128 + c8,                              \
                  wbase + (((unsigned)(ii)&7u) << 10));                    \
    } while (0)

#define CONSUME(i) do {                                                    \
      uint4 u = *(const uint4*)(wbase + (((unsigned)(i)&7u) << 10) + l * 16); \
      float4 v0 = unpack_bf16x4(u.x, u.y);                                 \
      float4 v1 = unpack_bf16x4(u.z, u.w);                                 \
      float e, p;                                                          \
      e = v0.x + xr0.x; e = fmaxf(e, 0.2f * e); p = e * at0.x;             \
      e = v0.y + xr0.y; e = fmaxf(e, 0.2f * e); p = fmaf(e, at0.y, p);     \
      e = v0.z + xr0.z; e = fmaxf(e, 0.2f * e); p = fmaf(e, at0.z, p);     \
      e = v0.w + xr0.w; e = fmaxf(e, 0.2f * e); p = fmaf(e, at0.w, p);     \
      e = v1.x + xr1.x; e = fmaxf(e, 0.2f * e); p = fmaf(e, at1.x, p);     \
      e = v1.y + xr1.y; e = fmaxf(e, 0.2f * e); p = fmaf(e, at1.y, p);     \
      e = v1.z + xr1.z; e = fmaxf(e, 0.2f * e); p = fmaf(e, at1.z, p);     \
      e = v1.w + xr1.w; e = fmaxf(e, 0.2f * e); p = fmaf(e, at1.w, p);     \
      p = quad_red(p);                                                     \
      float pe = ((i) < deg) ? __expf(p) : 0.f;                            \
      den += pe;                                                           \
      a0.x = fmaf(pe, v0.x, a0.x); a0.y = fmaf(pe, v0.y, a0.y);            \
      a0.z = fmaf(pe, v0.z, a0.z); a0.w = fmaf(pe, v0.w, a0.w);            \
      a1.x = fmaf(pe, v1.x, a1.x); a1.y = fmaf(pe, v1.y, a1.y);            \
      a1.z = fmaf(pe, v1.z, a1.z); a1.w = fmaf(pe, v1.w, a1.w);            \
    } while (0)

    const int mp = maxd < 64 ? maxd : 64;  // pipelined region
    const int pro = mp < 7 ? mp : 7;       // depth 7 < 8 slots (no collision)
    for (int i = 0; i < pro; ++i) STAGE(i);
    const int me = mp - 7;  // may be <= 0
    for (int i = 0; i < me; ++i) {
      STAGE(i + 7);
      asm volatile("s_waitcnt vmcnt(7)" ::: "memory");
      CONSUME(i);
    }

    // ---- prefetch NEXT node meta (latency hides under drain+tail+prologue)
    const int nb2 = nb + nstride;
    int node2 = nb2 + g;
    int nodec2 = node2 < NN ? node2 : NN - 1;
    float4 nxr0 = *(const float4*)&xr[(size_t)nodec2 * 128 + c8];
    float4 nxr1 = *(const float4*)&xr[(size_t)nodec2 * 128 + c8 + 4];
    int beg2 = offs[nodec2];
    int deg2 = offs[nodec2 + 1] - beg2;
    if (node2 >= NN) deg2 = 0;
    int n0, n1, n2, n3;
    { int a = beg2 + gl;      a = a < ETOT ? a : ETOT - 1; n0 = csr[a]; }
    { int a = beg2 + 16 + gl; a = a < ETOT ? a : ETOT - 1; n1 = csr[a]; }
    { int a = beg2 + 32 + gl; a = a < ETOT ? a : ETOT - 1; n2 = csr[a]; }
    { int a = beg2 + 48 + gl; a = a < ETOT ? a : ETOT - 1; n3 = csr[a]; }

    // ---- drain ----
    asm volatile("s_waitcnt vmcnt(0)" ::: "memory");
    for (int i = me > 0 ? me : 0; i < mp; ++i) CONSUME(i);

    // rare deg>64 tail: direct register gathers, unpipelined
    for (int i = 64; i < maxd; ++i) {
      int a = beg + i; a = a < ETOT ? a : ETOT - 1;
      int s = csr[a];
      if (i >= deg) s = 0;
      uint4 u = *(const uint4*)(xlh + (size_t)s * 128 + c8);
      float4 v0 = unpack_bf16x4(u.x, u.y);
      float4 v1 = unpack_bf16x4(u.z, u.w);
      float e, p;
      e = v0.x + xr0.x; e = fmaxf(e, 0.2f * e); p = e * at0.x;
      e = v0.y + xr0.y; e = fmaxf(e, 0.2f * e); p = fmaf(e, at0.y, p);
      e = v0.z + xr0.z; e = fmaxf(e, 0.2f * e); p = fmaf(e, at0.z, p);
      e = v0.w + xr0.w; e = fmaxf(e, 0.2f * e); p = fmaf(e, at0.w, p);
      e = v1.x + xr1.x; e = fmaxf(e, 0.2f * e); p = fmaf(e, at1.x, p);
      e = v1.y + xr1.y; e = fmaxf(e, 0.2f * e); p = fmaf(e, at1.y, p);
      e = v1.z + xr1.z; e = fmaxf(e, 0.2f * e); p = fmaf(e, at1.z, p);
      e = v1.w + xr1.w; e = fmaxf(e, 0.2f * e); p = fmaf(e, at1.w, p);
      p = quad_red(p);
      float pe = (i < deg) ? __expf(p) : 0.f;
      den += pe;
      a0.x = fmaf(pe, v0.x, a0.x); a0.y = fmaf(pe, v0.y, a0.y);
      a0.z = fmaf(pe, v0.z, a0.z); a0.w = fmaf(pe, v0.w, a0.w);
      a1.x = fmaf(pe, v1.x, a1.x); a1.y = fmaf(pe, v1.y, a1.y);
      a1.z = fmaf(pe, v1.z, a1.z); a1.w = fmaf(pe, v1.w, a1.w);
    }
#undef STAGE
#undef CONSUME

    if (node < NN) {
      float inv = 1.0f / den;
      float4 r0, r1;
      r0.x = a0.x * inv; r0.y = a0.y * inv; r0.z = a0.z * inv; r0.w = a0.w * inv;
      r1.x = a1.x * inv; r1.y = a1.y * inv; r1.z = a1.z * inv; r1.w = a1.w * inv;
      *(float4*)&out[(size_t)node * 128 + c8] = r0;
      *(float4*)&out[(size_t)node * 128 + c8 + 4] = r1;
    }

    // maxd2 shfl here: offs loads retired long ago -> lgkm wait is free
    int maxd2 = deg2;
    maxd2 = max(maxd2, __shfl_xor(maxd2, 16));
    maxd2 = max(maxd2, __shfl_xor(maxd2, 32));

    // rotate meta
    xr0 = nxr0; xr1 = nxr1;
    m0 = n0; m1 = n1; m2 = n2; m3 = n3;
    beg = beg2; deg = deg2; maxd = maxd2; node = node2;
  }
}

// ---------------- BN stats over out (sum, sumsq per channel) ----------------
__global__ __launch_bounds__(256) void bn_stats(const float* __restrict__ out,
                                                float* __restrict__ bn) {
  __shared__ float sb[256];
  int t = threadIdx.x;
  sb[t] = 0.f;
  __syncthreads();
  const int c4 = (t & 31) * 4;
  float4 s = make_float4(0, 0, 0, 0), q = make_float4(0, 0, 0, 0);
  const int total4 = NN * 32;
  for (int i = blockIdx.x * 256 + t; i < total4; i += gridDim.x * 256) {
    float4 o = ((const float4*)out)[i];
    s.x += o.x; s.y += o.y; s.z += o.z; s.w += o.w;
    q.x += o.x * o.x; q.y += o.y * o.y; q.z += o.z * o.z; q.w += o.w * o.w;
  }
  atomicAdd(&sb[c4 + 0], s.x);
  atomicAdd(&sb[c4 + 1], s.y);
  atomicAdd(&sb[c4 + 2], s.z);
  atomicAdd(&sb[c4 + 3], s.w);
  atomicAdd(&sb[128 + c4 + 0], q.x);
  atomicAdd(&sb[128 + c4 + 1], q.y);
  atomicAdd(&sb[128 + c4 + 2], q.z);
  atomicAdd(&sb[128 + c4 + 3], q.w);
  __syncthreads();
  atomicAdd(&bn[t], sb[t]);
}

// ---------------- BN-normalize + residual + ELU (in place on d_out) ----------
__global__ __launch_bounds__(256) void finalize(
    float* __restrict__ out, const float* __restrict__ x,
    const float* __restrict__ bn, const float* __restrict__ gamma,
    const float* __restrict__ beta) {
  __shared__ float smu[128], sgi[128];
  int t = threadIdx.x;
  if (t < 128) {
    float mu = bn[t] * (1.0f / NN);
    float var = bn[128 + t] * (1.0f / NN) - mu * mu;
    smu[t] = mu;
    sgi[t] = rsqrtf(var + 1e-5f) * gamma[t];
  }
  __syncthreads();
  const int total4 = NN * 32;
  for (int i = blockIdx.x * blockDim.x + threadIdx.x; i < total4;
       i += gridDim.x * blockDim.x) {
    int c4 = (i & 31) * 4;
    float4 o = ((const float4*)out)[i];
    float4 xv = ((const float4*)x)[i];
    float4 mu = *(const float4*)&smu[c4];
    float4 gi = *(const float4*)&sgi[c4];
    float4 b4 = *(const float4*)&beta[c4];
    float v;
    v = (o.x - mu.x) * gi.x + b4.x + xv.x; o.x = v > 0.f ? v : expm1f(v);
    v = (o.y - mu.y) * gi.y + b4.y + xv.y; o.y = v > 0.f ? v : expm1f(v);
    v = (o.z - mu.z) * gi.z + b4.z + xv.z; o.z = v > 0.f ? v : expm1f(v);
    v = (o.w - mu.w) * gi.w + b4.w + xv.w; o.w = v > 0.f ? v : expm1f(v);
    ((float4*)out)[i] = o;
  }
}

extern "C" void kernel_launch(void* const* d_in, const int* in_sizes, int n_in,
                              void* d_out, int out_size, void* d_ws, size_t ws_size,
                              hipStream_t stream) {
  const float* x    = (const float*)d_in[0];
  const int*   ei   = (const int*)d_in[1];
  const float* Wl   = (const float*)d_in[2];
  const float* bl   = (const float*)d_in[3];
  const float* Wr   = (const float*)d_in[4];
  const float* br   = (const float*)d_in[5];
  const float* att  = (const float*)d_in[6];
  const float* gam  = (const float*)d_in[8];
  const float* bet  = (const float*)d_in[9];
  float* out = (float*)d_out;

  unsigned short* xlh = (unsigned short*)d_ws;        // NN*128 bf16
  float* xr   = (float*)(xlh + (size_t)NN * 128);     // NN*128 f32
  int* offs   = (int*)(xr + (size_t)NN * 128);        // NN+4 ints
  int* cursor = offs + (NN + 4);                      // NN ints
  int* deg    = cursor + NN;                          // NN ints
  int* csr    = deg + NN;                             // ETOT ints
  float* bn   = (float*)(csr + ETOT);                 // 256 f32: sum | sumsq
  int* bsum   = (int*)(bn + 256);                     // 256 ints

  hipMemsetD32Async((hipDeviceptr_t)deg, 1, NN, stream);  // self-loop

  hipLaunchKernelGGL(gemm_count, dim3(GEMM_GRID + COUNT_BLOCKS), dim3(256), 0,
                     stream, x, Wl, bl, Wr, br, xlh, xr, ei, deg);
  hipLaunchKernelGGL(scanA, dim3(SCAN_BLOCKS), dim3(256), 0, stream, deg, bsum, bn);
  hipLaunchKernelGGL(scanB, dim3(SCAN_BLOCKS), dim3(256), 0, stream,
                     deg, bsum, offs, cursor);
  hipLaunchKernelGGL(fill_csr, dim3((ETOT + 255) / 256), dim3(256), 0, stream,
                     ei, cursor, csr);
  hipLaunchKernelGGL(aggregate, dim3(AGG_BLOCKS), dim3(256), 0, stream,
                     xlh, xr, offs, csr, att, out);
  hipLaunchKernelGGL(bn_stats, dim3(1024), dim3(256), 0, stream, out, bn);
  hipLaunchKernelGGL(finalize, dim3(2048), dim3(256), 0, stream, out, x, bn, gam, bet);
}